// Round 1
// baseline (2582.047 us; speedup 1.0000x reference)
//
#include <hip/hip_runtime.h>
#include <stdint.h>

typedef float f32x4 __attribute__((ext_vector_type(4)));
typedef int v4i __attribute__((ext_vector_type(4)));
typedef int v8i __attribute__((ext_vector_type(8)));

#define FP8MAX 448.0f

__device__ __forceinline__ float amax_scale(float amax) {
    return FP8MAX / fmaxf(amax, 1e-12f);
}

// ---------------- amax (|x| max over tensor) ----------------
__global__ void amax_kernel(const float* __restrict__ x, long n, float* __restrict__ out) {
    long idx = (long)blockIdx.x * blockDim.x + threadIdx.x;
    long stride = (long)gridDim.x * blockDim.x;
    float m = 0.0f;
    for (long j = idx * 4; j < n; j += stride * 4) {
        f32x4 v = *(const f32x4*)(x + j);
        m = fmaxf(m, fmaxf(fmaxf(__builtin_fabsf(v.x), __builtin_fabsf(v.y)),
                           fmaxf(__builtin_fabsf(v.z), __builtin_fabsf(v.w))));
    }
#pragma unroll
    for (int o = 32; o > 0; o >>= 1) m = fmaxf(m, __shfl_xor(m, o, 64));
    if ((threadIdx.x & 63) == 0) atomicMax((int*)out, __float_as_int(m));
}

// ---------------- quantize fp32 -> fp8 e4m3 (row-major, same layout) ----------------
__global__ void quant_kernel(const float* __restrict__ x, uint8_t* __restrict__ q,
                             const float* __restrict__ amaxp, long n) {
    const float s = amax_scale(*amaxp);
    long idx = (long)blockIdx.x * blockDim.x + threadIdx.x;
    long stride = (long)gridDim.x * blockDim.x;
    for (long j = idx * 4; j < n; j += stride * 4) {
        f32x4 v = *(const f32x4*)(x + j);
        int p0 = __builtin_amdgcn_cvt_pk_fp8_f32(v.x * s, v.y * s, 0, false);
        int p1 = __builtin_amdgcn_cvt_pk_fp8_f32(v.z * s, v.w * s, 0, false);
        *(uint32_t*)(q + j) = (uint32_t)(p0 & 0xffff) | ((uint32_t)p1 << 16);
    }
}

// ---------------- quantize + transpose: w[R][C] fp32 -> wqT[C][R] fp8 ----------------
__global__ void quant_transpose_kernel(const float* __restrict__ w, uint8_t* __restrict__ wqT,
                                       const float* __restrict__ amaxp, int R, int C) {
    __shared__ float tile[32][33];
    const float sc = amax_scale(*amaxp);
    const int col0 = blockIdx.x * 32;
    const int row0 = blockIdx.y * 32;
    const int tx = threadIdx.x & 31;
    const int ty = threadIdx.x >> 5;  // 0..7
#pragma unroll
    for (int i = 0; i < 4; i++)
        tile[ty + i * 8][tx] = w[(long)(row0 + ty + i * 8) * C + col0 + tx];
    __syncthreads();
    const int c  = threadIdx.x >> 3;        // 0..31 (output row = col0+c)
    const int kk = (threadIdx.x & 7) * 4;   // 0..28 (output col group)
    float v0 = tile[kk + 0][c] * sc, v1 = tile[kk + 1][c] * sc;
    float v2 = tile[kk + 2][c] * sc, v3 = tile[kk + 3][c] * sc;
    int p0 = __builtin_amdgcn_cvt_pk_fp8_f32(v0, v1, 0, false);
    int p1 = __builtin_amdgcn_cvt_pk_fp8_f32(v2, v3, 0, false);
    *(uint32_t*)(wqT + (long)(col0 + c) * R + row0 + kk) =
        (uint32_t)(p0 & 0xffff) | ((uint32_t)p1 << 16);
}

// ---------------- MX-fp8 GEMM: C[M][N] = dequant(A[M][K] @ Bt[N][K]^T) + bias ----------------
// 256x256 tile, BK=128 fp8 bytes, 512 threads = 8 waves (2M x 4N), wave tile 128x64.
// Deep pipeline: K-tile kt+1's 8 global_load_lds are issued at the TOP of K-tile kt
// and drained by a single per-wave vmcnt(0) fence 4 MFMA-phases later (~2200 cy >>
// HBM latency) just before kt's final barrier -- so the drain is nearly free, vs the
// old structure that drained every K-step at distance 0 (the ~35% MfmaUtil ceiling).
// Each K-tile = 4 barrier-locked phases of 8 mfma_scale_f32_16x16x128_f8f6f4 with
// setprio(1) around the MFMA cluster (T5). LDS rows are 128B = 32 banks; 16B-unit
// XOR swizzle (unit ^= row&7) keeps every ds_read_b128 at the b128 phase floor while
// global_load_lds stays a contiguous lane*16B DMA (wave-uniform-base constraint).
__device__ __forceinline__ void lds_dma16(const void* g, void* l) {
    __builtin_amdgcn_global_load_lds((__attribute__((address_space(1))) void*)(void*)g,
                                     (__attribute__((address_space(3))) void*)l, 16, 0, 0);
}

template <bool RELU, bool AMAX>
__global__ __launch_bounds__(512, 2) void gemm_mxfp8_kernel(
    const uint8_t* __restrict__ A, const uint8_t* __restrict__ Bt,
    float* __restrict__ C, const float* __restrict__ bias,
    const float* __restrict__ amaxA, const float* __restrict__ amaxB,
    float* __restrict__ amaxOut, int M, int N, int K) {
    __shared__ __align__(16) uint8_t As[2][256 * 128];   // 64 KB
    __shared__ __align__(16) uint8_t Bs[2][256 * 128];   // 64 KB

    const int t = threadIdx.x;
    const int lane = t & 63;
    const int wave = t >> 6;          // 0..7
    const int wm = wave >> 2;         // 0..1 -> 128 rows
    const int wn = wave & 3;          // 0..3 -> 64 cols

    // XCD-aware bijective swizzle (grid % 8 == 0 for all our shapes)
    int bid = (int)blockIdx.x;
    bid = (bid & 7) * ((int)gridDim.x >> 3) + (bid >> 3);
    const int nbn = N >> 8;
    const int bm = bid / nbn;
    const int bn = bid - bm * nbn;

    // staging: load d (0..3) covers tile rows d*64 + (t>>3); storage unit t&7 holds
    // global unit (t&7) ^ (row&7); row&7 == (t>>3)&7 (d*64 is a multiple of 8).
    const int rs = t >> 3;                        // 0..63
    const int us = (t & 7) ^ (rs & 7);
    const uint8_t* ag = A + (long)(bm * 256 + rs) * K + us * 16;
    const uint8_t* bg = Bt + (long)(bn * 256 + rs) * K + us * 16;

    auto stage = [&](int buf, int kt) {
        const uint8_t* a_ = ag + (long)kt * 128;
        const uint8_t* b_ = bg + (long)kt * 128;
        uint8_t* al_ = &As[buf][t * 16];
        uint8_t* bl_ = &Bs[buf][t * 16];
#pragma unroll
        for (int d = 0; d < 4; d++) {
            lds_dma16(a_ + (long)d * 64 * K, al_ + d * 8192);
            lds_dma16(b_ + (long)d * 64 * K, bl_ + d * 8192);
        }
    };

    // fragment read addressing (16x16x128 fp8: lane holds row=lane&15, 32 k-bytes
    // at k-group g=lane>>4; swizzled 16B units)
    const int lrow = lane & 15;
    const int g = lane >> 4;
    const int x7 = lane & 7;
    const int u0 = ((2 * g + 0) ^ x7) * 16;
    const int u1 = ((2 * g + 1) ^ x7) * 16;
    const int roA = (wm * 128 + lrow) * 128;
    const int roB = (wn * 64 + lrow) * 128;

    f32x4 acc[8][4] = {};
    const int NT = K >> 7;

    // prologue: stage K-tile 0 into buf0; all-waves rendezvous after own drain
    stage(0, 0);
    asm volatile("s_waitcnt vmcnt(0)" ::: "memory");
    __builtin_amdgcn_s_barrier();
    asm volatile("" ::: "memory");

    for (int kt = 0; kt < NT; ++kt) {
        const int b = kt & 1;
        const uint8_t* Ab = As[b];
        const uint8_t* Bb = Bs[b];
        // issue next K-tile's loads first: max issue->drain distance (4 phases)
        if (kt + 1 < NT) stage(b ^ 1, kt + 1);

        // B fragments resident for the whole K-tile (8 x ds_read_b128)
        v8i bf[4];
#pragma unroll
        for (int j = 0; j < 4; j++) {
            const uint8_t* p = Bb + roB + j * 2048;
            *(v4i*)&bf[j] = *(const v4i*)(p + u0);
            *((v4i*)&bf[j] + 1) = *(const v4i*)(p + u1);
        }
        // 4 phases; phase ph: A row-frags 2ph,2ph+1 x all 4 B cols = 8 MFMA
#pragma unroll
        for (int ph = 0; ph < 4; ph++) {
            v8i a0, a1;
            const uint8_t* pa0 = Ab + roA + (2 * ph + 0) * 2048;
            const uint8_t* pa1 = Ab + roA + (2 * ph + 1) * 2048;
            *(v4i*)&a0 = *(const v4i*)(pa0 + u0);
            *((v4i*)&a0 + 1) = *(const v4i*)(pa0 + u1);
            *(v4i*)&a1 = *(const v4i*)(pa1 + u0);
            *((v4i*)&a1 + 1) = *(const v4i*)(pa1 + u1);
            __builtin_amdgcn_s_barrier();
            __builtin_amdgcn_s_setprio(1);
#pragma unroll
            for (int j = 0; j < 4; j++) {
                acc[2 * ph + 0][j] = __builtin_amdgcn_mfma_scale_f32_16x16x128_f8f6f4(
                    a0, bf[j], acc[2 * ph + 0][j], 0, 0,
                    0, 0x7f7f7f7f, 0, 0x7f7f7f7f);     // unit E8M0 scales => exact fp8
                acc[2 * ph + 1][j] = __builtin_amdgcn_mfma_scale_f32_16x16x128_f8f6f4(
                    a1, bf[j], acc[2 * ph + 1][j], 0, 0,
                    0, 0x7f7f7f7f, 0, 0x7f7f7f7f);
            }
            __builtin_amdgcn_s_setprio(0);
            if (ph == 3) {
                // K-tile boundary: own loads for kt+1 done before the rendezvous,
                // so after this barrier every wave's DMA writes are LDS-visible.
                // (no-op on the last K-tile: nothing outstanding)
                asm volatile("s_waitcnt vmcnt(0)" ::: "memory");
            }
            __builtin_amdgcn_s_barrier();
            if (ph == 3) asm volatile("" ::: "memory");  // pin next tile's mem ops after barrier
        }
    }

    // epilogue: dequant scale + bias (+relu) (+fused amax); 16x16 C/D layout:
    // col = lane&15, row = (lane>>4)*4 + reg (dtype-independent, m89)
    const float inv = 1.0f / (amax_scale(*amaxA) * amax_scale(*amaxB));
    const int rg = (lane >> 4) * 4;
    const int cl = lane & 15;
    const int orow = bm * 256 + wm * 128 + rg;
    const int ocol = bn * 256 + wn * 64 + cl;
    float lmax = 0.0f;
#pragma unroll
    for (int j = 0; j < 4; j++) {
        const float bv = bias[ocol + j * 16];
#pragma unroll
        for (int i = 0; i < 8; i++) {
#pragma unroll
            for (int r = 0; r < 4; r++) {
                float v = acc[i][j][r] * inv + bv;
                if (RELU) v = fmaxf(v, 0.0f);
                C[(long)(orow + i * 16 + r) * N + ocol + j * 16] = v;
                if (AMAX) lmax = fmaxf(lmax, __builtin_fabsf(v));
            }
        }
    }
    if (AMAX) {
#pragma unroll
        for (int o = 32; o > 0; o >>= 1) lmax = fmaxf(lmax, __shfl_xor(lmax, o, 64));
        if (lane == 0) atomicMax((int*)amaxOut, __float_as_int(lmax));
    }
}

extern "C" void kernel_launch(void* const* d_in, const int* in_sizes, int n_in,
                              void* d_out, int out_size, void* d_ws, size_t ws_size,
                              hipStream_t stream) {
    const float* x  = (const float*)d_in[0];
    const float* w1 = (const float*)d_in[1];
    const float* b1 = (const float*)d_in[2];
    const float* w2 = (const float*)d_in[3];
    const float* b2 = (const float*)d_in[4];
    float* out = (float*)d_out;

    const int N1 = in_sizes[2];       // 16384
    const int N2 = in_sizes[4];       // 4096
    const int K1 = in_sizes[1] / N1;  // 4096
    const int M  = in_sizes[0] / K1;  // 8192

    uint8_t* ws = (uint8_t*)d_ws;
    float* amax_x  = (float*)(ws + 0);
    float* amax_w1 = (float*)(ws + 4);
    float* amax_w2 = (float*)(ws + 8);
    float* amax_h  = (float*)(ws + 12);
    size_t off = 256;
    uint8_t* xq   = ws + off; off += (size_t)M * K1;        // 33.5 MB
    uint8_t* w1qT = ws + off; off += (size_t)K1 * N1;       // 67 MB
    uint8_t* w2qT = ws + off; off += (size_t)N1 * N2;       // 67 MB
    uint8_t* hq   = ws + off; off += (size_t)M * N1;        // 134 MB
    float*   h    = (float*)(ws + off); off += (size_t)M * N1 * 4;  // 537 MB

    hipMemsetAsync(d_ws, 0, 256, stream);  // zero amax slots (ws is poisoned 0xAA)

    amax_kernel<<<1024, 256, 0, stream>>>(x,  (long)M * K1,  amax_x);
    amax_kernel<<<1024, 256, 0, stream>>>(w1, (long)K1 * N1, amax_w1);
    amax_kernel<<<1024, 256, 0, stream>>>(w2, (long)N1 * N2, amax_w2);

    quant_kernel<<<2048, 256, 0, stream>>>(x, xq, amax_x, (long)M * K1);
    quant_transpose_kernel<<<dim3(N1 / 32, K1 / 32), 256, 0, stream>>>(w1, w1qT, amax_w1, K1, N1);
    quant_transpose_kernel<<<dim3(N2 / 32, N1 / 32), 256, 0, stream>>>(w2, w2qT, amax_w2, N1, N2);

    gemm_mxfp8_kernel<true, true><<<(M / 256) * (N1 / 256), 512, 0, stream>>>(
        xq, w1qT, h, b1, amax_x, amax_w1, amax_h, M, N1, K1);

    quant_kernel<<<4096, 256, 0, stream>>>(h, hq, amax_h, (long)M * N1);

    gemm_mxfp8_kernel<false, false><<<(M / 256) * (N2 / 256), 512, 0, stream>>>(
        hq, w2qT, out, b2, amax_h, amax_w2, nullptr, M, N2, N1);
}

// Round 2
// 2380.930 us; speedup vs baseline: 1.0845x; 1.0845x over previous
//
#include <hip/hip_runtime.h>
#include <stdint.h>

typedef float f32x4 __attribute__((ext_vector_type(4)));
typedef int v4i __attribute__((ext_vector_type(4)));
typedef int v8i __attribute__((ext_vector_type(8)));

#define FP8MAX 448.0f

__device__ __forceinline__ float amax_scale(float amax) {
    return FP8MAX / fmaxf(amax, 1e-12f);
}

// ---------------- amax (|x| max over tensor) ----------------
__global__ void amax_kernel(const float* __restrict__ x, long n, float* __restrict__ out) {
    long idx = (long)blockIdx.x * blockDim.x + threadIdx.x;
    long stride = (long)gridDim.x * blockDim.x;
    float m = 0.0f;
    for (long j = idx * 4; j < n; j += stride * 4) {
        f32x4 v = *(const f32x4*)(x + j);
        m = fmaxf(m, fmaxf(fmaxf(__builtin_fabsf(v.x), __builtin_fabsf(v.y)),
                           fmaxf(__builtin_fabsf(v.z), __builtin_fabsf(v.w))));
    }
#pragma unroll
    for (int o = 32; o > 0; o >>= 1) m = fmaxf(m, __shfl_xor(m, o, 64));
    if ((threadIdx.x & 63) == 0) atomicMax((int*)out, __float_as_int(m));
}

// ---------------- quantize fp32 -> fp8 e4m3 (row-major, same layout) ----------------
__global__ void quant_kernel(const float* __restrict__ x, uint8_t* __restrict__ q,
                             const float* __restrict__ amaxp, long n) {
    const float s = amax_scale(*amaxp);
    long idx = (long)blockIdx.x * blockDim.x + threadIdx.x;
    long stride = (long)gridDim.x * blockDim.x;
    for (long j = idx * 4; j < n; j += stride * 4) {
        f32x4 v = *(const f32x4*)(x + j);
        int p0 = __builtin_amdgcn_cvt_pk_fp8_f32(v.x * s, v.y * s, 0, false);
        int p1 = __builtin_amdgcn_cvt_pk_fp8_f32(v.z * s, v.w * s, 0, false);
        *(uint32_t*)(q + j) = (uint32_t)(p0 & 0xffff) | ((uint32_t)p1 << 16);
    }
}

// ---------------- quantize + transpose: w[R][C] fp32 -> wqT[C][R] fp8 ----------------
__global__ void quant_transpose_kernel(const float* __restrict__ w, uint8_t* __restrict__ wqT,
                                       const float* __restrict__ amaxp, int R, int C) {
    __shared__ float tile[32][33];
    const float sc = amax_scale(*amaxp);
    const int col0 = blockIdx.x * 32;
    const int row0 = blockIdx.y * 32;
    const int tx = threadIdx.x & 31;
    const int ty = threadIdx.x >> 5;  // 0..7
#pragma unroll
    for (int i = 0; i < 4; i++)
        tile[ty + i * 8][tx] = w[(long)(row0 + ty + i * 8) * C + col0 + tx];
    __syncthreads();
    const int c  = threadIdx.x >> 3;        // 0..31 (output row = col0+c)
    const int kk = (threadIdx.x & 7) * 4;   // 0..28 (output col group)
    float v0 = tile[kk + 0][c] * sc, v1 = tile[kk + 1][c] * sc;
    float v2 = tile[kk + 2][c] * sc, v3 = tile[kk + 3][c] * sc;
    int p0 = __builtin_amdgcn_cvt_pk_fp8_f32(v0, v1, 0, false);
    int p1 = __builtin_amdgcn_cvt_pk_fp8_f32(v2, v3, 0, false);
    *(uint32_t*)(wqT + (long)(col0 + c) * R + row0 + kk) =
        (uint32_t)(p0 & 0xffff) | ((uint32_t)p1 << 16);
}

// ---------------- MX-fp8 GEMM: C[M][N] = dequant(A[M][K] @ Bt[N][K]^T) + bias ----------------
// 256x256 tile, BK=128 fp8 bytes, 512 threads = 8 waves (2M x 4N), wave tile 128x64.
// T3+T4 schedule (the m196/m218 lesson: counted vmcnt + spread stage issues; coarse
// burst + vmcnt(0) is WORSE than no pipeline):
//   per iteration kt (4 phases, computing buf b, staging tile kt+1 into b^1):
//     ph0 io: 8 ds_read B-frags + 4 ds_read A-frags | issue B-stage x4
//     ph1 io: 4 ds_read A-frags                     | issue A-stage d0,d2 (rows 0-63,128-191)
//     ph2 io: 4 ds_read A-frags (late-A region)     | issue A-stage d1,d3 (rows 64-127,192-255)
//     ph3 io: 4 ds_read A-frags                     | (no stage)
//   each phase: io window -> s_barrier -> setprio(1) 8 MFMA setprio(0) -> s_barrier
//   drains: vmcnt(6) after ph1 MFMAs (waits ONLY prev tile's late-A pair, issued ~3
//   MFMA-phases earlier), vmcnt(2) after ph3 (waits next tile's B+early-A, issued 2-3
//   phases earlier). In-flight ledger (in-order per-wave): enter kt with [lateA(kt) x2];
//   ph0 +B(kt+1)x4; ph1 +earlyA(kt+1)x2 -> vmcnt(6) drains lateA(kt); ph2 +lateA(kt+1)x2
//   -> ph3 vmcnt(2) drains B+earlyA(kt+1). Consumption order matches stage-age order, so
//   every wait targets loads issued >=2 MFMA-phases (~1100+ cy) earlier >> HBM latency.
//   Staging is unconditional (last tile re-stages itself) so the ledger never changes shape.
// LDS rows are 128B = 32 banks; 16B-unit XOR swizzle (unit ^= row&7) keeps ds_read_b128
// at the b128 phase floor while global_load_lds stays a contiguous lane*16B DMA.
__device__ __forceinline__ void lds_dma16(const void* g, void* l) {
    __builtin_amdgcn_global_load_lds((__attribute__((address_space(1))) void*)(void*)g,
                                     (__attribute__((address_space(3))) void*)l, 16, 0, 0);
}

template <bool RELU, bool AMAX>
__global__ __launch_bounds__(512, 2) void gemm_mxfp8_kernel(
    const uint8_t* __restrict__ A, const uint8_t* __restrict__ Bt,
    float* __restrict__ C, const float* __restrict__ bias,
    const float* __restrict__ amaxA, const float* __restrict__ amaxB,
    float* __restrict__ amaxOut, int M, int N, int K) {
    __shared__ __align__(16) uint8_t As[2][256 * 128];   // 64 KB
    __shared__ __align__(16) uint8_t Bs[2][256 * 128];   // 64 KB

    const int t = threadIdx.x;
    const int lane = t & 63;
    const int wave = t >> 6;          // 0..7
    const int wm = wave >> 2;         // 0..1 -> 128 rows
    const int wn = wave & 3;          // 0..3 -> 64 cols

    // XCD-aware bijective swizzle (grid % 8 == 0 for all our shapes)
    int bid = (int)blockIdx.x;
    bid = (bid & 7) * ((int)gridDim.x >> 3) + (bid >> 3);
    const int nbn = N >> 8;
    const int bm = bid / nbn;
    const int bn = bid - bm * nbn;

    // staging: load d (0..3) covers tile rows d*64 + (t>>3); storage unit t&7 holds
    // global unit (t&7) ^ (row&7); row&7 == (t>>3)&7 (d*64 is a multiple of 8).
    const int rs = t >> 3;                        // 0..63
    const int us = (t & 7) ^ (rs & 7);
    const uint8_t* ag = A + (long)(bm * 256 + rs) * K + us * 16;
    const uint8_t* bg = Bt + (long)(bn * 256 + rs) * K + us * 16;

    auto stA = [&](int buf, int kt, int d) {
        lds_dma16(ag + (long)kt * 128 + (long)d * 64 * K, &As[buf][t * 16 + d * 8192]);
    };
    auto stB = [&](int buf, int kt, int d) {
        lds_dma16(bg + (long)kt * 128 + (long)d * 64 * K, &Bs[buf][t * 16 + d * 8192]);
    };

    // fragment read addressing (16x16x128 fp8: lane holds row=lane&15, 32 k-bytes
    // at k-group g=lane>>4; swizzled 16B units)
    const int lrow = lane & 15;
    const int g = lane >> 4;
    const int x7 = lane & 7;
    const int u0 = ((2 * g + 0) ^ x7) * 16;
    const int u1 = ((2 * g + 1) ^ x7) * 16;
    const int roA = (wm * 128 + lrow) * 128;
    const int roB = (wn * 64 + lrow) * 128;

    f32x4 acc[8][4] = {};
    const int NT = K >> 7;

    // prologue: stage tile 0 in ledger order (B x4, earlyA x2, lateA x2); drain all
    // but lateA -> enter steady state with [lateA(0) x2] in flight.
    stB(0, 0, 0); stB(0, 0, 1); stB(0, 0, 2); stB(0, 0, 3);
    stA(0, 0, 0); stA(0, 0, 2);
    stA(0, 0, 1); stA(0, 0, 3);
    asm volatile("s_waitcnt vmcnt(2)" ::: "memory");
    __builtin_amdgcn_s_barrier();
    asm volatile("" ::: "memory");

    for (int kt = 0; kt < NT; ++kt) {
        const int b = kt & 1;
        const int nb = b ^ 1;
        const uint8_t* __restrict__ Ab = &As[b][0];
        const uint8_t* __restrict__ Bb = &Bs[b][0];
        const int ktn = (kt + 1 < NT) ? kt + 1 : NT - 1;  // unconditional ledger

        v8i bf[4];
#pragma unroll
        for (int p = 0; p < 4; ++p) {
            // ---- io window ----
            if (p == 0) {
#pragma unroll
                for (int j = 0; j < 4; ++j) {
                    const uint8_t* q = Bb + roB + j * 2048;
                    *(v4i*)&bf[j] = *(const v4i*)(q + u0);
                    *((v4i*)&bf[j] + 1) = *(const v4i*)(q + u1);
                }
            }
            v8i a0, a1;
            {
                const uint8_t* pa0 = Ab + roA + (2 * p + 0) * 2048;
                const uint8_t* pa1 = Ab + roA + (2 * p + 1) * 2048;
                *(v4i*)&a0 = *(const v4i*)(pa0 + u0);
                *((v4i*)&a0 + 1) = *(const v4i*)(pa0 + u1);
                *(v4i*)&a1 = *(const v4i*)(pa1 + u0);
                *((v4i*)&a1 + 1) = *(const v4i*)(pa1 + u1);
            }
            if (p == 0)      { stB(nb, ktn, 0); stB(nb, ktn, 1); stB(nb, ktn, 2); stB(nb, ktn, 3); }
            else if (p == 1) { stA(nb, ktn, 0); stA(nb, ktn, 2); }
            else if (p == 2) { stA(nb, ktn, 1); stA(nb, ktn, 3); }
            asm volatile("" ::: "memory");
            __builtin_amdgcn_s_barrier();
            // ---- MFMA window (compiler inserts counted lgkm waits for the ds_reads) ----
            __builtin_amdgcn_s_setprio(1);
#pragma unroll
            for (int j = 0; j < 4; ++j) {
                acc[2 * p + 0][j] = __builtin_amdgcn_mfma_scale_f32_16x16x128_f8f6f4(
                    a0, bf[j], acc[2 * p + 0][j], 0, 0,
                    0, 0x7f7f7f7f, 0, 0x7f7f7f7f);     // unit E8M0 scales => exact fp8
                acc[2 * p + 1][j] = __builtin_amdgcn_mfma_scale_f32_16x16x128_f8f6f4(
                    a1, bf[j], acc[2 * p + 1][j], 0, 0,
                    0, 0x7f7f7f7f, 0, 0x7f7f7f7f);
            }
            __builtin_amdgcn_s_setprio(0);
            if (p == 1) asm volatile("s_waitcnt vmcnt(6)" ::: "memory");  // drain lateA(kt)
            if (p == 3) asm volatile("s_waitcnt vmcnt(2)" ::: "memory");  // drain B+earlyA(kt+1)
            asm volatile("" ::: "memory");
            __builtin_amdgcn_s_barrier();
            asm volatile("" ::: "memory");
        }
    }
    asm volatile("s_waitcnt vmcnt(0)" ::: "memory");  // retire redundant last-tile stages

    // epilogue: dequant scale + bias (+relu) (+fused amax); 16x16 C/D layout:
    // col = lane&15, row = (lane>>4)*4 + reg (dtype-independent, m89)
    const float inv = 1.0f / (amax_scale(*amaxA) * amax_scale(*amaxB));
    const int rg = (lane >> 4) * 4;
    const int cl = lane & 15;
    const int orow = bm * 256 + wm * 128 + rg;
    const int ocol = bn * 256 + wn * 64 + cl;
    float lmax = 0.0f;
#pragma unroll
    for (int j = 0; j < 4; j++) {
        const float bv = bias[ocol + j * 16];
#pragma unroll
        for (int i = 0; i < 8; i++) {
#pragma unroll
            for (int r = 0; r < 4; r++) {
                float v = acc[i][j][r] * inv + bv;
                if (RELU) v = fmaxf(v, 0.0f);
                C[(long)(orow + i * 16 + r) * N + ocol + j * 16] = v;
                if (AMAX) lmax = fmaxf(lmax, __builtin_fabsf(v));
            }
        }
    }
    if (AMAX) {
#pragma unroll
        for (int o = 32; o > 0; o >>= 1) lmax = fmaxf(lmax, __shfl_xor(lmax, o, 64));
        if (lane == 0) atomicMax((int*)amaxOut, __float_as_int(lmax));
    }
}

extern "C" void kernel_launch(void* const* d_in, const int* in_sizes, int n_in,
                              void* d_out, int out_size, void* d_ws, size_t ws_size,
                              hipStream_t stream) {
    const float* x  = (const float*)d_in[0];
    const float* w1 = (const float*)d_in[1];
    const float* b1 = (const float*)d_in[2];
    const float* w2 = (const float*)d_in[3];
    const float* b2 = (const float*)d_in[4];
    float* out = (float*)d_out;

    const int N1 = in_sizes[2];       // 16384
    const int N2 = in_sizes[4];       // 4096
    const int K1 = in_sizes[1] / N1;  // 4096
    const int M  = in_sizes[0] / K1;  // 8192

    uint8_t* ws = (uint8_t*)d_ws;
    float* amax_x  = (float*)(ws + 0);
    float* amax_w1 = (float*)(ws + 4);
    float* amax_w2 = (float*)(ws + 8);
    float* amax_h  = (float*)(ws + 12);
    size_t off = 256;
    uint8_t* xq   = ws + off; off += (size_t)M * K1;        // 33.5 MB
    uint8_t* w1qT = ws + off; off += (size_t)K1 * N1;       // 67 MB
    uint8_t* w2qT = ws + off; off += (size_t)N1 * N2;       // 67 MB
    uint8_t* hq   = ws + off; off += (size_t)M * N1;        // 134 MB
    float*   h    = (float*)(ws + off); off += (size_t)M * N1 * 4;  // 537 MB

    hipMemsetAsync(d_ws, 0, 256, stream);  // zero amax slots (ws is poisoned 0xAA)

    amax_kernel<<<1024, 256, 0, stream>>>(x,  (long)M * K1,  amax_x);
    amax_kernel<<<1024, 256, 0, stream>>>(w1, (long)K1 * N1, amax_w1);
    amax_kernel<<<1024, 256, 0, stream>>>(w2, (long)N1 * N2, amax_w2);

    quant_kernel<<<2048, 256, 0, stream>>>(x, xq, amax_x, (long)M * K1);
    quant_transpose_kernel<<<dim3(N1 / 32, K1 / 32), 256, 0, stream>>>(w1, w1qT, amax_w1, K1, N1);
    quant_transpose_kernel<<<dim3(N2 / 32, N1 / 32), 256, 0, stream>>>(w2, w2qT, amax_w2, N1, N2);

    gemm_mxfp8_kernel<true, true><<<(M / 256) * (N1 / 256), 512, 0, stream>>>(
        xq, w1qT, h, b1, amax_x, amax_w1, amax_h, M, N1, K1);

    quant_kernel<<<4096, 256, 0, stream>>>(h, hq, amax_h, (long)M * N1);

    gemm_mxfp8_kernel<false, false><<<(M / 256) * (N2 / 256), 512, 0, stream>>>(
        hq, w2qT, out, b2, amax_h, amax_w2, nullptr, M, N2, N1);
}